// Round 10
// baseline (222.671 us; speedup 1.0000x reference)
//
#include <hip/hip_runtime.h>
#include <stdint.h>
#include <math.h>

#define NH 16
#define DH 64
#define SEQ 2048
#define DMODEL 1024

typedef short short8 __attribute__((ext_vector_type(8)));
typedef short short4v __attribute__((ext_vector_type(4)));
typedef float f32x4 __attribute__((ext_vector_type(4)));
typedef __bf16 bf16x4 __attribute__((ext_vector_type(4)));

__device__ __forceinline__ short f2bf(float f) {
  __bf16 h = (__bf16)f;
  return __builtin_bit_cast(short, h);
}
__device__ __forceinline__ short4v cvt4(f32x4 v) {
  bf16x4 b = __builtin_convertvector(v, bf16x4);
  return __builtin_bit_cast(short4v, b);
}
__device__ __forceinline__ float fast_exp2(float x) {
#if __has_builtin(__builtin_amdgcn_exp2f)
  return __builtin_amdgcn_exp2f(x);
#else
  return exp2f(x);
#endif
}

typedef const __attribute__((address_space(1))) uint32_t* gp_t;
typedef __attribute__((address_space(3))) uint32_t* lp_t;
__device__ __forceinline__ void async16(const short* g, short* l) {
  __builtin_amdgcn_global_load_lds((gp_t)g, (lp_t)l, 16, 0, 0);
}

// ---- fused prep: x fp32->bf16 | w_in^T bf16 | w_out^T bf16 (one launch) ----
__device__ __forceinline__ void transpose_tile(const float* __restrict__ in,
                                               short* __restrict__ out, int R, int C,
                                               int t, int tilesX, int tid) {
  __shared__ float tile[32][33];
  const int tx = tid & 31, ty = tid >> 5;  // 32 x 8
  const int c0 = (t % tilesX) * 32, r0 = (t / tilesX) * 32;
#pragma unroll
  for (int i = 0; i < 4; ++i)
    tile[ty + i * 8][tx] = in[(size_t)(r0 + ty + i * 8) * C + c0 + tx];
  __syncthreads();
#pragma unroll
  for (int i = 0; i < 4; ++i)
    out[(size_t)(c0 + ty + i * 8) * R + r0 + tx] = f2bf(tile[tx][ty + i * 8]);
}

__global__ void k_prep(const float* __restrict__ x, short* __restrict__ xb,
                       const float* __restrict__ w_in, short* __restrict__ w_in_t,
                       const float* __restrict__ w_out, short* __restrict__ w_out_t) {
  const int tid = threadIdx.x;
  const int blk = blockIdx.x;
  if (blk < 4096) {  // x convert
    const int i = blk * 256 + tid;
    f32x4 v = ((const f32x4*)x)[i];
    ((short4v*)xb)[i] = cvt4(v);
  } else if (blk < 4096 + 3072) {  // w_in [1024,3072] -> [3072,1024]
    transpose_tile(w_in, w_in_t, 1024, 3072, blk - 4096, 96, tid);
  } else {  // w_out [1024,1024] -> transpose
    transpose_tile(w_out, w_out_t, 1024, 1024, blk - 7168, 32, tid);
  }
}

// ---------------- GEMM: C[M,N] = A[M,K=1024] * Bt[N,K]^T + bias ------------
// BK=64: 16 K-iters x 32 MFMA. LDS tiles 128x64, XOR-chunk-swizzled so
// global_load_lds (linear, wave-uniform-base) + conflict-free b128 reads.
template <int MODE>
__launch_bounds__(256, 3)
__global__ void k_gemm(const short* __restrict__ A, const short* __restrict__ Bt,
                       const float* __restrict__ bias, float* __restrict__ Cf,
                       short* __restrict__ qo, short* __restrict__ ko,
                       short* __restrict__ vo) {
  constexpr int KD = 1024;
  __shared__ __align__(16) short As[128 * 64];  // 16 KB
  __shared__ __align__(16) short Bs[128 * 64];  // 16 KB
  const int tid = threadIdx.x;
  const int wave = tid >> 6, lane = tid & 63;
  const int quad = lane >> 4, l16 = lane & 15;
  const int wm = wave >> 1, wn = wave & 1;
  const int tM = blockIdx.y * 128, tN = blockIdx.x * 128;

  const short* pA[4];
  const short* pB[4];
  short* lA[4];
  short* lB[4];
#pragma unroll
  for (int t = 0; t < 4; ++t) {
    const int c = t * 256 + tid;
    const int row = c >> 3, gch = (c & 7) ^ (row & 7);
    pA[t] = A + (size_t)(tM + row) * KD + gch * 8;
    pB[t] = Bt + (size_t)(tN + row) * KD + gch * 8;
    lA[t] = &As[c * 8];
    lB[t] = &Bs[c * 8];
  }

  const int sw = l16 & 7;
  const int col0 = (quad ^ sw) << 3;
  const int col1 = col0 ^ 32;

  f32x4 acc[4][4] = {};

  for (int k0 = 0; k0 < KD; k0 += 64) {
    __syncthreads();
#pragma unroll
    for (int t = 0; t < 4; ++t) {
      async16(pA[t] + k0, lA[t]);
      async16(pB[t] + k0, lB[t]);
    }
    __syncthreads();
#pragma unroll
    for (int kh = 0; kh < 2; ++kh) {
      const int col = kh ? col1 : col0;
      short8 af[4], bfr[4];
#pragma unroll
      for (int i = 0; i < 4; ++i)
        af[i] = *(const short8*)&As[(wm * 64 + i * 16 + l16) * 64 + col];
#pragma unroll
      for (int i = 0; i < 4; ++i)
        bfr[i] = *(const short8*)&Bs[(wn * 64 + i * 16 + l16) * 64 + col];
#pragma unroll
      for (int i = 0; i < 4; ++i)
#pragma unroll
        for (int j = 0; j < 4; ++j)
          acc[i][j] = __builtin_amdgcn_mfma_f32_16x16x32_bf16(af[i], bfr[j], acc[i][j], 0, 0, 0);
    }
  }

  const int rbase = tM + wm * 64 + quad * 4;
#pragma unroll
  for (int i = 0; i < 4; ++i) {
#pragma unroll
    for (int j = 0; j < 4; ++j) {
      const int col = tN + wn * 64 + j * 16 + l16;
      const float bi = bias[col];
      if (MODE == 0) {
        const int which = col >> 10;  // uniform per block
        const int h = (col & 1023) >> 6, d = col & 63;
        if (which == 2) {
          const int row0 = rbase + i * 16;
          const int b = row0 >> 11, li0 = row0 & 2047;
          f32x4 t;
#pragma unroll
          for (int rr = 0; rr < 4; ++rr) t[rr] = acc[i][j][rr] + bi;
          *(short4v*)&vo[(((size_t)(b * NH + h)) * DH + d) * SEQ + li0] = cvt4(t);
        } else {
          short* dst = (which == 0) ? qo : ko;
#pragma unroll
          for (int rr = 0; rr < 4; ++rr) {
            const int row = rbase + i * 16 + rr;
            const int b = row >> 11, li = row & 2047;
            dst[(((size_t)(b * NH + h)) * SEQ + li) * DH + d] = f2bf(acc[i][j][rr] + bi);
          }
        }
      } else {
#pragma unroll
        for (int rr = 0; rr < 4; ++rr) {
          const int row = rbase + i * 16 + rr;
          Cf[(size_t)row * DMODEL + col] = acc[i][j][rr] + bi;
        }
      }
    }
  }
}

// -------- flash attention: R7 skeleton + register-direct V ----------------
// 1D grid 1024, LPT: qt = 31-(bx>>5), bh = bx&31; 4 blocks/CU.
// K double-buffered in LDS (zero cover for K). V loaded straight to VGPRs at
// tile start — BEFORE the K staging async16s, so V-use waits vmcnt(2) and
// never drains the prefetch. S-MFMA + softmax (~500cyc) covers V latency.
// LDS = 24 KB (Ks dbuf 16K + Ps 8K); ~45% less LDS read traffic vs R7.
__launch_bounds__(256, 4)
__global__ void k_attn(const short* __restrict__ q, const short* __restrict__ k,
                       const short* __restrict__ vt, short* __restrict__ o) {
  __shared__ __align__(16) short Ks[2][64 * 64];  // 16 KB
  __shared__ __align__(16) short Ps[4][16 * 64];  // 8 KB, per-wave P [q][key]
  const int tid = threadIdx.x;
  const int wave = tid >> 6, lane = tid & 63;
  const int quad = lane >> 4, l16 = lane & 15;
  const int sw = l16 & 7;
  const int qt = 31 - (blockIdx.x >> 5);
  const int bh = blockIdx.x & 31;
  const int h = bh & (NH - 1);
  const size_t base = (size_t)bh * SEQ * DH;
  const float LOG2E = 1.44269504088896f;
  const float slope2 = exp2f(-0.5f * (float)(h + 1)) * LOG2E;
  const float scale2 = 0.125f * LOG2E;
  const float FM = 12.0f;  // fixed softmax max; cancels in O/l exactly

  // K staging chunks: c = t*256+tid, row=c>>3, ch=(c&7)^(row&7); lds = c*16B
  const int c0i = tid, c1i = 256 + tid;
  const int r0 = c0i >> 3, ch0 = (c0i & 7) ^ (r0 & 7);
  const int r1 = c1i >> 3, ch1 = (c1i & 7) ^ (r1 & 7);
  const int qk_off0 = r0 * DH + ch0 * 8;
  const int qk_off1 = r1 * DH + ch1 * 8;

  const int col0 = ((quad ^ sw) << 3);
  const int col1 = col0 ^ 32;
  int psoff[4];
#pragma unroll
  for (int in = 0; in < 4; ++in)
    psoff[in] = l16 * 64 + (((2 * in + (quad >> 1)) ^ sw) << 3) + (quad & 1) * 4;
  const int qlim4 = wave * 16 + l16 - 4 * quad;  // diag: keep 16*in+r <= qlim4

  const int q0 = qt * 64;
  const int qrow = q0 + wave * 16 + l16;  // each lane owns ONE q-row
  // Q fragment: direct global one-time load (B-operand layout)
  const short* qp = q + base + (size_t)qrow * DH + quad * 8;
  const short8 qb0 = *(const short8*)qp;
  const short8 qb1 = *(const short8*)(qp + 32);

  short8 ones;
#pragma unroll
  for (int j = 0; j < 8; ++j) ones[j] = (short)0x3F80;  // bf16 1.0

  f32x4 accO[4] = {};
  f32x4 accL = {};
  const float qoff = -slope2 * (float)qrow - FM + slope2 * (float)(4 * quad);
  float inoff[4];
#pragma unroll
  for (int in = 0; in < 4; ++in)
    inoff[in] = qoff + slope2 * (float)(16 * in);
  const float s64 = slope2 * 64.0f;
  float rc[4];
#pragma unroll
  for (int r = 0; r < 4; ++r) rc[r] = slope2 * (float)r;

  const short* kp = k + base;  // advances 64 rows per tile
  // V^T register-frag base: row d = i*16+l16, key offset quad*8 (+32)
  const short* vK = vt + base + (size_t)l16 * SEQ + quad * 8;

  // stage K tile 0 into buf 0
  async16(kp + qk_off0, &Ks[0][c0i * 8]);
  async16(kp + qk_off1, &Ks[0][c1i * 8]);
  kp += 64 * DH;
  __syncthreads();

  for (int kt = 0; kt <= qt; ++kt) {
    const int cur = kt & 1, nxt = cur ^ 1;

    // V fragments for THIS tile: global->VGPR, issued first (vmcnt ordering)
    short8 vr[8];
    {
      const short* p = vK + kt * 64;
#pragma unroll
      for (int i = 0; i < 4; ++i) {
        vr[2 * i] = *(const short8*)(p + (size_t)(i * 16) * SEQ);
        vr[2 * i + 1] = *(const short8*)(p + (size_t)(i * 16) * SEQ + 32);
      }
    }
    if (kt < qt) {  // K prefetch kt+1 (after V loads: V-use waits vmcnt(2))
      async16(kp + qk_off0, &Ks[nxt][c0i * 8]);
      async16(kp + qk_off1, &Ks[nxt][c1i * 8]);
      kp += 64 * DH;
    }

    // S^T = K Q^T : lane holds keys 16*in+4*quad+r for q-row l16
    f32x4 s[4];
#pragma unroll
    for (int in = 0; in < 4; ++in) {
      const short8 ka0 = *(const short8*)&Ks[cur][(in * 16 + l16) * 64 + col0];
      const short8 ka1 = *(const short8*)&Ks[cur][(in * 16 + l16) * 64 + col1];
      f32x4 t = {};
      t = __builtin_amdgcn_mfma_f32_16x16x32_bf16(ka0, qb0, t, 0, 0, 0);
      t = __builtin_amdgcn_mfma_f32_16x16x32_bf16(ka1, qb1, t, 0, 0, 0);
      s[in] = t;
    }

    if (kt == qt) {  // diagonal: causal mask
#pragma unroll
      for (int in = 0; in < 4; ++in) {
        f32x4 p;
#pragma unroll
        for (int r = 0; r < 4; ++r) {
          float val = fast_exp2(fmaf(s[in][r], scale2, inoff[in] + rc[r]));
          p[r] = (16 * in + r <= qlim4) ? val : 0.f;
        }
        *(short4v*)&Ps[wave][psoff[in]] = cvt4(p);
      }
    } else {
#pragma unroll
      for (int in = 0; in < 4; ++in) {
        f32x4 p;
#pragma unroll
        for (int r = 0; r < 4; ++r)
          p[r] = fast_exp2(fmaf(s[in][r], scale2, inoff[in] + rc[r]));
        *(short4v*)&Ps[wave][psoff[in]] = cvt4(p);
      }
    }
#pragma unroll
    for (int in = 0; in < 4; ++in) inoff[in] += s64;

    // O^T += V^T P^T ; row-sum via ones-row MFMA. V frags from registers.
    const short8 pa0 = *(const short8*)&Ps[wave][l16 * 64 + col0];
    const short8 pa1 = *(const short8*)&Ps[wave][l16 * 64 + col1];
    accL = __builtin_amdgcn_mfma_f32_16x16x32_bf16(ones, pa0, accL, 0, 0, 0);
    accL = __builtin_amdgcn_mfma_f32_16x16x32_bf16(ones, pa1, accL, 0, 0, 0);
#pragma unroll
    for (int i = 0; i < 4; ++i) {
      accO[i] = __builtin_amdgcn_mfma_f32_16x16x32_bf16(vr[2 * i], pa0, accO[i], 0, 0, 0);
      accO[i] = __builtin_amdgcn_mfma_f32_16x16x32_bf16(vr[2 * i + 1], pa1, accO[i], 0, 0, 0);
    }
    __syncthreads();  // publishes prefetched K buf + frees cur
  }

  const float inv = 1.0f / accL[0];
  const int b = bh >> 4;
  short* ob = o + ((((size_t)b * SEQ + qrow) * NH + h) * DH + 4 * quad);
#pragma unroll
  for (int i = 0; i < 4; ++i) {
    f32x4 t;
#pragma unroll
    for (int r = 0; r < 4; ++r) t[r] = accO[i][r] * inv;
    *(short4v*)&ob[16 * i] = cvt4(t);
  }
}

extern "C" void kernel_launch(void* const* d_in, const int* in_sizes, int n_in,
                              void* d_out, int out_size, void* d_ws, size_t ws_size,
                              hipStream_t stream) {
  const float* x = (const float*)d_in[0];      // [2,2048,1024]
  const float* w_in = (const float*)d_in[1];   // [1024,3072]
  const float* b_in = (const float*)d_in[2];   // [3072]
  const float* w_out = (const float*)d_in[3];  // [1024,1024]
  const float* b_out = (const float*)d_in[4];  // [1024]
  float* out = (float*)d_out;

  char* ws = (char*)d_ws;
  short* xb = (short*)(ws);                     // 8 MB  bf16 x
  short* w_in_t = (short*)(ws + (8u << 20));    // 6 MB  bf16 w_in^T [3072][1024]
  short* w_out_t = (short*)(ws + (14u << 20));  // 2 MB  bf16 w_out^T
  short* qv = (short*)(ws + (16u << 20));       // 8 MB  [B,H,L,dh]
  short* kv = (short*)(ws + (24u << 20));       // 8 MB  [B,H,L,dh]
  short* vv = (short*)(ws + (32u << 20));       // 8 MB  [B,H,dh,L] (transposed)
  short* ao = (short*)(ws + (40u << 20));       // 8 MB  attn out [B,L,D] bf16

  k_prep<<<8192, 256, 0, stream>>>(x, xb, w_in, w_in_t, w_out, w_out_t);
  k_gemm<0><<<dim3(24, 32), 256, 0, stream>>>(xb, w_in_t, b_in, nullptr, qv, kv, vv);
  k_attn<<<1024, 256, 0, stream>>>(qv, kv, vv, ao);
  k_gemm<1><<<dim3(8, 32), 256, 0, stream>>>(ao, w_out_t, b_out, out, nullptr, nullptr, nullptr);
}

// Round 11
// 170.292 us; speedup vs baseline: 1.3076x; 1.3076x over previous
//
#include <hip/hip_runtime.h>
#include <stdint.h>
#include <math.h>

#define NH 16
#define DH 64
#define SEQ 2048
#define DMODEL 1024

typedef short short8 __attribute__((ext_vector_type(8)));
typedef short short4v __attribute__((ext_vector_type(4)));
typedef float f32x4 __attribute__((ext_vector_type(4)));
typedef __bf16 bf16x4 __attribute__((ext_vector_type(4)));

__device__ __forceinline__ short f2bf(float f) {
  __bf16 h = (__bf16)f;
  return __builtin_bit_cast(short, h);
}
__device__ __forceinline__ short4v cvt4(f32x4 v) {
  bf16x4 b = __builtin_convertvector(v, bf16x4);
  return __builtin_bit_cast(short4v, b);
}
__device__ __forceinline__ float fast_exp2(float x) {
#if __has_builtin(__builtin_amdgcn_exp2f)
  return __builtin_amdgcn_exp2f(x);
#else
  return exp2f(x);
#endif
}

// k=16 bf16 MFMA (A 2 regs, B 2 regs, C 4) — instruction verified in ISA doc §10.
__device__ __forceinline__ f32x4 mfma16(short4v a, short4v b, f32x4 c) {
#if __has_builtin(__builtin_amdgcn_mfma_f32_16x16x16bf16_1k)
  return __builtin_amdgcn_mfma_f32_16x16x16bf16_1k(a, b, c, 0, 0, 0);
#else
  asm volatile("v_mfma_f32_16x16x16_bf16 %0, %1, %2, %0" : "+v"(c) : "v"(a), "v"(b));
  return c;
#endif
}

typedef const __attribute__((address_space(1))) uint32_t* gp_t;
typedef __attribute__((address_space(3))) uint32_t* lp_t;
__device__ __forceinline__ void async16(const short* g, short* l) {
  __builtin_amdgcn_global_load_lds((gp_t)g, (lp_t)l, 16, 0, 0);
}

// ---- fused prep: x fp32->bf16 | w_in^T bf16 | w_out^T bf16 (one launch) ----
__device__ __forceinline__ void transpose_tile(const float* __restrict__ in,
                                               short* __restrict__ out, int R, int C,
                                               int t, int tilesX, int tid) {
  __shared__ float tile[32][33];
  const int tx = tid & 31, ty = tid >> 5;  // 32 x 8
  const int c0 = (t % tilesX) * 32, r0 = (t / tilesX) * 32;
#pragma unroll
  for (int i = 0; i < 4; ++i)
    tile[ty + i * 8][tx] = in[(size_t)(r0 + ty + i * 8) * C + c0 + tx];
  __syncthreads();
#pragma unroll
  for (int i = 0; i < 4; ++i)
    out[(size_t)(c0 + ty + i * 8) * R + r0 + tx] = f2bf(tile[tx][ty + i * 8]);
}

__global__ void k_prep(const float* __restrict__ x, short* __restrict__ xb,
                       const float* __restrict__ w_in, short* __restrict__ w_in_t,
                       const float* __restrict__ w_out, short* __restrict__ w_out_t) {
  const int tid = threadIdx.x;
  const int blk = blockIdx.x;
  if (blk < 4096) {  // x convert
    const int i = blk * 256 + tid;
    f32x4 v = ((const f32x4*)x)[i];
    ((short4v*)xb)[i] = cvt4(v);
  } else if (blk < 4096 + 3072) {  // w_in [1024,3072] -> [3072,1024]
    transpose_tile(w_in, w_in_t, 1024, 3072, blk - 4096, 96, tid);
  } else {  // w_out [1024,1024] -> transpose
    transpose_tile(w_out, w_out_t, 1024, 1024, blk - 7168, 32, tid);
  }
}

// ---------------- GEMM: C[M,N] = A[M,K=1024] * Bt[N,K]^T + bias ------------
// BK=64: 16 K-iters x 32 MFMA. LDS tiles 128x64, XOR-chunk-swizzled so
// global_load_lds (linear, wave-uniform-base) + conflict-free b128 reads.
template <int MODE>
__launch_bounds__(256, 3)
__global__ void k_gemm(const short* __restrict__ A, const short* __restrict__ Bt,
                       const float* __restrict__ bias, float* __restrict__ Cf,
                       short* __restrict__ qo, short* __restrict__ ko,
                       short* __restrict__ vo) {
  constexpr int KD = 1024;
  __shared__ __align__(16) short As[128 * 64];  // 16 KB
  __shared__ __align__(16) short Bs[128 * 64];  // 16 KB
  const int tid = threadIdx.x;
  const int wave = tid >> 6, lane = tid & 63;
  const int quad = lane >> 4, l16 = lane & 15;
  const int wm = wave >> 1, wn = wave & 1;
  const int tM = blockIdx.y * 128, tN = blockIdx.x * 128;

  const short* pA[4];
  const short* pB[4];
  short* lA[4];
  short* lB[4];
#pragma unroll
  for (int t = 0; t < 4; ++t) {
    const int c = t * 256 + tid;
    const int row = c >> 3, gch = (c & 7) ^ (row & 7);
    pA[t] = A + (size_t)(tM + row) * KD + gch * 8;
    pB[t] = Bt + (size_t)(tN + row) * KD + gch * 8;
    lA[t] = &As[c * 8];
    lB[t] = &Bs[c * 8];
  }

  const int sw = l16 & 7;
  const int col0 = (quad ^ sw) << 3;
  const int col1 = col0 ^ 32;

  f32x4 acc[4][4] = {};

  for (int k0 = 0; k0 < KD; k0 += 64) {
    __syncthreads();
#pragma unroll
    for (int t = 0; t < 4; ++t) {
      async16(pA[t] + k0, lA[t]);
      async16(pB[t] + k0, lB[t]);
    }
    __syncthreads();
#pragma unroll
    for (int kh = 0; kh < 2; ++kh) {
      const int col = kh ? col1 : col0;
      short8 af[4], bfr[4];
#pragma unroll
      for (int i = 0; i < 4; ++i)
        af[i] = *(const short8*)&As[(wm * 64 + i * 16 + l16) * 64 + col];
#pragma unroll
      for (int i = 0; i < 4; ++i)
        bfr[i] = *(const short8*)&Bs[(wn * 64 + i * 16 + l16) * 64 + col];
#pragma unroll
      for (int i = 0; i < 4; ++i)
#pragma unroll
        for (int j = 0; j < 4; ++j)
          acc[i][j] = __builtin_amdgcn_mfma_f32_16x16x32_bf16(af[i], bfr[j], acc[i][j], 0, 0, 0);
    }
  }

  const int rbase = tM + wm * 64 + quad * 4;
#pragma unroll
  for (int i = 0; i < 4; ++i) {
#pragma unroll
    for (int j = 0; j < 4; ++j) {
      const int col = tN + wn * 64 + j * 16 + l16;
      const float bi = bias[col];
      if (MODE == 0) {
        const int which = col >> 10;  // uniform per block
        const int h = (col & 1023) >> 6, d = col & 63;
        if (which == 2) {
          const int row0 = rbase + i * 16;
          const int b = row0 >> 11, li0 = row0 & 2047;
          f32x4 t;
#pragma unroll
          for (int rr = 0; rr < 4; ++rr) t[rr] = acc[i][j][rr] + bi;
          *(short4v*)&vo[(((size_t)(b * NH + h)) * DH + d) * SEQ + li0] = cvt4(t);
        } else {
          short* dst = (which == 0) ? qo : ko;
#pragma unroll
          for (int rr = 0; rr < 4; ++rr) {
            const int row = rbase + i * 16 + rr;
            const int b = row >> 11, li = row & 2047;
            dst[(((size_t)(b * NH + h)) * SEQ + li) * DH + d] = f2bf(acc[i][j][rr] + bi);
          }
        }
      } else {
#pragma unroll
        for (int rr = 0; rr < 4; ++rr) {
          const int row = rbase + i * 16 + rr;
          Cf[(size_t)row * DMODEL + col] = acc[i][j][rr] + bi;
        }
      }
    }
  }
}

// -------- flash attention: key-sliced waves, no Ps round-trip --------------
// 1D grid 1024, LPT: qt = 31-(bx>>5), bh = bx&31. K,V double-buffered LDS
// (R7 staging). Wave w owns keys [16w,16w+16) x ALL 64 q-rows:
//   - K frag reads 2 KB/wave/step (vs 8), V 2 KB (vs 8), NO Ps traffic.
//   - S^T C-layout (row=4q+r=key_local, col=l16=q) IS the 16x16x16 PV
//     B-operand layout (k=4q+j, n=l16): pack f32->bf16, feed directly.
// accO is partial (per key-slice); cross-wave LDS reduction once per block.
__launch_bounds__(256, 3)
__global__ void k_attn(const short* __restrict__ q, const short* __restrict__ k,
                       const short* __restrict__ vt, short* __restrict__ o) {
  __shared__ __align__(16) short Ks[2][64 * 64];  // 16 KB
  __shared__ __align__(16) short Vs[2][64 * 64];  // 16 KB, V^T tile [d][key]
  const int tid = threadIdx.x;
  const int wave = tid >> 6, lane = tid & 63;
  const int quad = lane >> 4, l16 = lane & 15;
  const int sw = l16 & 7;
  const int qt = 31 - (blockIdx.x >> 5);
  const int bh = blockIdx.x & 31;
  const int h = bh & (NH - 1);
  const size_t base = (size_t)bh * SEQ * DH;
  const float LOG2E = 1.44269504088896f;
  const float slope2 = exp2f(-0.5f * (float)(h + 1)) * LOG2E;
  const float scale2 = 0.125f * LOG2E;
  const float FM = 12.0f;  // fixed softmax max; cancels in O/l exactly

  // staging chunks (R7): c = t*256+tid, row=c>>3, ch=(c&7)^(row&7); lds=c*16B
  const int c0i = tid, c1i = 256 + tid;
  const int r0 = c0i >> 3, ch0 = (c0i & 7) ^ (r0 & 7);
  const int r1 = c1i >> 3, ch1 = (c1i & 7) ^ (r1 & 7);
  const int qk_off0 = r0 * DH + ch0 * 8;
  const int qk_off1 = r1 * DH + ch1 * 8;
  const int v_off0 = r0 * SEQ + ch0 * 8;
  const int v_off1 = r1 * SEQ + ch1 * 8;

  // K frag (A-op 16x16x32): row = 16*wave + l16, k-col chunk quad^sw (^4)
  const int krow = (16 * wave + l16) * 64;
  const int kcol0 = (quad ^ sw) << 3;
  const int kcol1 = kcol0 ^ 32;
  // V frag (A-op 16x16x16): row = 16i+l16, key chunk (2w+(quad>>1))^sw, +4(quad&1)
  const int vcol = (((2 * wave + (quad >> 1)) ^ sw) << 3) + (quad & 1) * 4;

  const int q0 = qt * 64;
  // Q frags (B-op 16x16x32), 4 q-groups, one-time direct global load
  short8 qf0[4], qf1[4];
#pragma unroll
  for (int g = 0; g < 4; ++g) {
    const short* qp = q + base + (size_t)(q0 + 16 * g + l16) * DH + quad * 8;
    qf0[g] = *(const short8*)qp;
    qf1[g] = *(const short8*)(qp + 32);
  }

  f32x4 accO[4][4] = {};  // [g][i]: O[d=16i+4quad+r][q=16g+l16], partial over keys
  float lsum[4] = {0.f, 0.f, 0.f, 0.f};

  // exponent = s*scale2 + slope2*(key - qrow) - FM
  // key = kb + 16w + 4quad + r ; qrow = q0 + 16g + l16
  float kb_r[4];
#pragma unroll
  for (int r = 0; r < 4; ++r)
    kb_r[r] = slope2 * (float)(16 * wave + 4 * quad + r) - FM;
  float gq[4];
#pragma unroll
  for (int g = 0; g < 4; ++g)
    gq[g] = -slope2 * (float)(q0 + 16 * g + l16);
  const float s64 = slope2 * 64.0f;
  const int keybase = 16 * wave + 4 * quad;  // diag mask: keybase+r <= 16g+l16

  const short* kp = k + base;
  const short* vp = vt + base;

  // stage tile 0 into buf 0
  async16(kp + qk_off0, &Ks[0][c0i * 8]);
  async16(kp + qk_off1, &Ks[0][c1i * 8]);
  async16(vp + v_off0, &Vs[0][c0i * 8]);
  async16(vp + v_off1, &Vs[0][c1i * 8]);
  kp += 64 * DH;
  vp += 64;
  __syncthreads();

  for (int kt = 0; kt <= qt; ++kt) {
    const int cur = kt & 1, nxt = cur ^ 1;
    if (kt < qt) {  // prefetch before compute
      async16(kp + qk_off0, &Ks[nxt][c0i * 8]);
      async16(kp + qk_off1, &Ks[nxt][c1i * 8]);
      async16(vp + v_off0, &Vs[nxt][c0i * 8]);
      async16(vp + v_off1, &Vs[nxt][c1i * 8]);
      kp += 64 * DH;
      vp += 64;
    }

    // wave's K slice (2 KB) and V slice (2 KB)
    const short8 ka0 = *(const short8*)&Ks[cur][krow + kcol0];
    const short8 ka1 = *(const short8*)&Ks[cur][krow + kcol1];
    short4v va[4];
#pragma unroll
    for (int i = 0; i < 4; ++i)
      va[i] = *(const short4v*)&Vs[cur][(16 * i + l16) * 64 + vcol];

    const bool diag = (kt == qt);
#pragma unroll
    for (int g = 0; g < 4; ++g) {
      // S^T slice: C[key_local=4quad+r][q=l16] for q-group g
      f32x4 s = {};
      s = __builtin_amdgcn_mfma_f32_16x16x32_bf16(ka0, qf0[g], s, 0, 0, 0);
      s = __builtin_amdgcn_mfma_f32_16x16x32_bf16(ka1, qf1[g], s, 0, 0, 0);
      f32x4 p;
      if (diag) {
        const int qloc = 16 * g + l16;
#pragma unroll
        for (int r = 0; r < 4; ++r) {
          float val = fast_exp2(fmaf(s[r], scale2, kb_r[r] + gq[g]));
          p[r] = (keybase + r <= qloc) ? val : 0.f;
        }
      } else {
#pragma unroll
        for (int r = 0; r < 4; ++r)
          p[r] = fast_exp2(fmaf(s[r], scale2, kb_r[r] + gq[g]));
      }
      lsum[g] += p[0] + p[1] + p[2] + p[3];
      const short4v pb = cvt4(p);  // == PV B-operand frag, no LDS round-trip
#pragma unroll
      for (int i = 0; i < 4; ++i) accO[g][i] = mfma16(va[i], pb, accO[g][i]);
    }
#pragma unroll
    for (int r = 0; r < 4; ++r) kb_r[r] += s64;
    __syncthreads();  // publishes prefetched bufs + frees cur
  }

  // ---- cross-wave reduction (accO partial over key-slices) ----
  f32x4* rb4 = (f32x4*)&Ks[0][0];  // 16 KB: [ (g*4+i)*64 + lane ]
  float* lb = (float*)&Vs[0][0];   // 1 KB:  [ g*64 + lane ]
  if (wave == 0) {
#pragma unroll
    for (int g = 0; g < 4; ++g) {
#pragma unroll
      for (int i = 0; i < 4; ++i) rb4[(g * 4 + i) * 64 + lane] = accO[g][i];
      lb[g * 64 + lane] = lsum[g];
    }
  }
  __syncthreads();
  if (wave == 1) {
#pragma unroll
    for (int g = 0; g < 4; ++g) {
#pragma unroll
      for (int i = 0; i < 4; ++i) {
        accO[g][i] += rb4[(g * 4 + i) * 64 + lane];
        rb4[(g * 4 + i) * 64 + lane] = accO[g][i];
      }
      lsum[g] += lb[g * 64 + lane];
      lb[g * 64 + lane] = lsum[g];
    }
  }
  __syncthreads();
  if (wave == 2) {
#pragma unroll
    for (int g = 0; g < 4; ++g) {
#pragma unroll
      for (int i = 0; i < 4; ++i) {
        accO[g][i] += rb4[(g * 4 + i) * 64 + lane];
        rb4[(g * 4 + i) * 64 + lane] = accO[g][i];
      }
      lsum[g] += lb[g * 64 + lane];
      lb[g * 64 + lane] = lsum[g];
    }
  }
  __syncthreads();
  if (wave == 3) {
    const int b = bh >> 4;
#pragma unroll
    for (int g = 0; g < 4; ++g) {
#pragma unroll
      for (int i = 0; i < 4; ++i) accO[g][i] += rb4[(g * 4 + i) * 64 + lane];
      lsum[g] += lb[g * 64 + lane];
      // cross-quad lsum reduction (each quad held 4 of the 16 slice-keys)
      lsum[g] += __shfl_xor(lsum[g], 16, 64);
      lsum[g] += __shfl_xor(lsum[g], 32, 64);
      const float inv = 1.0f / lsum[g];
      const int qrow = q0 + 16 * g + l16;
      short* ob = o + (((size_t)b * SEQ + qrow) * NH + h) * DH + 4 * quad;
#pragma unroll
      for (int i = 0; i < 4; ++i) {
        f32x4 t;
#pragma unroll
        for (int r = 0; r < 4; ++r) t[r] = accO[g][i][r] * inv;
        *(short4v*)&ob[16 * i] = cvt4(t);  // d = 16i+4quad+r contiguous
      }
    }
  }
}

extern "C" void kernel_launch(void* const* d_in, const int* in_sizes, int n_in,
                              void* d_out, int out_size, void* d_ws, size_t ws_size,
                              hipStream_t stream) {
  const float* x = (const float*)d_in[0];      // [2,2048,1024]
  const float* w_in = (const float*)d_in[1];   // [1024,3072]
  const float* b_in = (const float*)d_in[2];   // [3072]
  const float* w_out = (const float*)d_in[3];  // [1024,1024]
  const float* b_out = (const float*)d_in[4];  // [1024]
  float* out = (float*)d_out;

  char* ws = (char*)d_ws;
  short* xb = (short*)(ws);                     // 8 MB  bf16 x
  short* w_in_t = (short*)(ws + (8u << 20));    // 6 MB  bf16 w_in^T [3072][1024]
  short* w_out_t = (short*)(ws + (14u << 20));  // 2 MB  bf16 w_out^T
  short* qv = (short*)(ws + (16u << 20));       // 8 MB  [B,H,L,dh]
  short* kv = (short*)(ws + (24u << 20));       // 8 MB  [B,H,L,dh]
  short* vv = (short*)(ws + (32u << 20));       // 8 MB  [B,H,dh,L] (transposed)
  short* ao = (short*)(ws + (40u << 20));       // 8 MB  attn out [B,L,D] bf16

  k_prep<<<8192, 256, 0, stream>>>(x, xb, w_in, w_in_t, w_out, w_out_t);
  k_gemm<0><<<dim3(24, 32), 256, 0, stream>>>(xb, w_in_t, b_in, nullptr, qv, kv, vv);
  k_attn<<<1024, 256, 0, stream>>>(qv, kv, vv, ao);
  k_gemm<1><<<dim3(8, 32), 256, 0, stream>>>(ao, w_out_t, b_out, out, nullptr, nullptr, nullptr);
}